// Round 3
// baseline (218.299 us; speedup 1.0000x reference)
//
#include <hip/hip_runtime.h>
#include <math.h>

#define NA 8192
#define NE 32768
#define JSPLIT 64
#define JCHUNK (NA / JSPLIT) /* 128 */

// ---- workspace layout (4-byte element offsets) ----
#define WS_DEG      0                      // int  NA
#define WS_CSUM     (WS_DEG + NA)          // f32  NA
#define WS_SVEC     (WS_CSUM + NA)         // f32  3NA
#define WS_LOSS     (WS_SVEC + 3*NA)       // f32  4
#define WS_ZERO_END (WS_LOSS + 4)          // zero everything below this
#define WS_POS2     (WS_ZERO_END)          // float4 NA ((5NA+4)*4 B is 16B-aligned)
#define WS_POS1A    (WS_POS2 + 4*NA)       // f32  3NA
#define WS_POS1     (WS_POS1A + 3*NA)      // f32  3NA
#define WS_VIOL     (WS_POS1 + 3*NA)       // f32  NA
#define WS_RAD      (WS_VIOL + NA)         // f32  NA (vdw*0.8)

// ---- chemistry tables (types present: {1,6,7,8,9,15,16,17}) ----
__device__ __forceinline__ float maxval_of(int z) {
    switch (z) {
        case 1: return 1.f; case 6: return 4.f; case 7: return 3.f; case 8: return 2.f;
        case 9: return 1.f; case 15: return 5.f; case 16: return 6.f; case 17: return 1.f;
        case 35: return 1.f; case 53: return 1.f; default: return 4.f;
    }
}
__device__ __forceinline__ float vdw_of(int z) {
    switch (z) {
        case 1: return 1.2f; case 6: return 1.7f; case 7: return 1.55f; case 8: return 1.52f;
        case 9: return 1.47f; case 15: return 1.8f; case 16: return 1.8f; case 17: return 1.75f;
        case 35: return 1.85f; case 53: return 1.98f; default: return 1.6f;
    }
}
__device__ __forceinline__ float bond_of(int a, int b) {
    int lo = a < b ? a : b, hi = a < b ? b : a;
    switch (lo * 64 + hi) {
        case 6*64+6:   return 1.54f;
        case 6*64+7:   return 1.47f;
        case 6*64+8:   return 1.43f;
        case 6*64+16:  return 1.82f;
        case 6*64+9:   return 1.35f;
        case 6*64+17:  return 1.77f;
        case 1*64+6:   return 1.09f;
        case 7*64+7:   return 1.45f;
        case 7*64+8:   return 1.40f;
        case 1*64+7:   return 1.01f;
        case 8*64+8:   return 1.48f;
        case 1*64+8:   return 0.96f;
        case 16*64+16: return 2.05f;
        case 8*64+15:  return 1.63f;
        default:       return 1.5f;
    }
}

__device__ __forceinline__ float wave_reduce_sum(float x) {
    #pragma unroll
    for (int off = 32; off > 0; off >>= 1) x += __shfl_down(x, off);
    return x;  // valid in lane 0 of each wave
}

// ---- 1. out-degree histogram ----
__global__ void k_degree(const int* __restrict__ row, int* __restrict__ deg) {
    int e = blockIdx.x * 256 + threadIdx.x;
    if (e < NE) atomicAdd(&deg[row[e]], 1);
}

// ---- 2. per-atom prep: violation, radii, init pos1a/pos1/pos2, valence loss ----
__global__ void k_prep(const int* __restrict__ deg, const int* __restrict__ types,
                       const float* __restrict__ pos,
                       float* __restrict__ viol, float* __restrict__ rad08,
                       float* __restrict__ pos1a, float* __restrict__ pos1,
                       float4* __restrict__ pos2, float* __restrict__ lossAcc) {
    int r = blockIdx.x * 256 + threadIdx.x;
    float v = 0.f;
    if (r < NA) {
        int z = types[r];
        v = fmaxf((float)deg[r] - maxval_of(z), 0.f);
        viol[r] = v;
        float r08 = vdw_of(z) * 0.8f;
        rad08[r] = r08;
        float x = pos[3*r], y = pos[3*r+1], zc = pos[3*r+2];
        pos1a[3*r] = x; pos1a[3*r+1] = y; pos1a[3*r+2] = zc;
        pos1[3*r]  = x; pos1[3*r+1]  = y; pos1[3*r+2]  = zc;
        pos2[r] = make_float4(x, y, zc, r08);
    }
    float part = wave_reduce_sum(v * v);
    if ((threadIdx.x & 63) == 0) atomicAdd(&lossAcc[0], part);
}

// ---- 3. valence push pass A: edge-parallel, all neighbors from original pos ----
// Sequential-scan semantics approximated to first order (displacements are ~1e-3
// vs ~10 A distances; total approx error ~3e-5 on positions).
__global__ void k_pushA(const int* __restrict__ row, const int* __restrict__ col,
                        const float* __restrict__ pos, const float* __restrict__ viol,
                        float* __restrict__ pos1a) {
    int e = blockIdx.x * 256 + threadIdx.x;
    if (e >= NE) return;
    int r = row[e];
    float v = viol[r];
    if (v <= 0.f) return;
    int c = col[e];
    if (c == r) return;                       // self-edge: zero displacement
    float dx = pos[3*r]   - pos[3*c];
    float dy = pos[3*r+1] - pos[3*c+1];
    float dz = pos[3*r+2] - pos[3*c+2];
    float dist = sqrtf(dx*dx + dy*dy + dz*dz) + 1e-8f;
    float sc = v * 1e-3f / dist;
    atomicAdd(&pos1a[3*r],   dx * sc);
    atomicAdd(&pos1a[3*r+1], dy * sc);
    atomicAdd(&pos1a[3*r+2], dz * sc);
}

// ---- 4. valence push pass B: c<r neighbors read pass-A result ----
// Accumulates into pos1 (bond gather source) AND pos2 (float4 running position).
__global__ void k_pushB(const int* __restrict__ row, const int* __restrict__ col,
                        const float* __restrict__ pos, const float* __restrict__ viol,
                        const float* __restrict__ pos1a,
                        float* __restrict__ pos1, float* __restrict__ pos2f) {
    int e = blockIdx.x * 256 + threadIdx.x;
    if (e >= NE) return;
    int r = row[e];
    float v = viol[r];
    if (v <= 0.f) return;
    int c = col[e];
    if (c == r) return;
    float qx, qy, qz;
    if (c < r) { qx = pos1a[3*c]; qy = pos1a[3*c+1]; qz = pos1a[3*c+2]; }
    else       { qx = pos[3*c];   qy = pos[3*c+1];   qz = pos[3*c+2]; }
    float dx = pos[3*r]   - qx;
    float dy = pos[3*r+1] - qy;
    float dz = pos[3*r+2] - qz;
    float dist = sqrtf(dx*dx + dy*dy + dz*dz) + 1e-8f;
    float sc = v * 1e-3f / dist;
    float ax = dx * sc, ay = dy * sc, az = dz * sc;
    atomicAdd(&pos1[3*r],   ax);
    atomicAdd(&pos1[3*r+1], ay);
    atomicAdd(&pos1[3*r+2], az);
    atomicAdd(&pos2f[4*r],   ax);
    atomicAdd(&pos2f[4*r+1], ay);
    atomicAdd(&pos2f[4*r+2], az);
}

// ---- 5. bond-length correction: gather from pos1, atomic scatter into pos2 ----
__global__ void k_bond(const int* __restrict__ row, const int* __restrict__ col,
                       const int* __restrict__ types, const float* __restrict__ pos1,
                       float* __restrict__ pos2f, float* __restrict__ lossAcc) {
    int e = blockIdx.x * 256 + threadIdx.x;
    float d2acc = 0.f;
    if (e < NE) {
        int r = row[e], c = col[e];
        float bx = pos1[3*r]   - pos1[3*c];
        float by = pos1[3*r+1] - pos1[3*c+1];
        float bz = pos1[3*r+2] - pos1[3*c+2];
        float cur = sqrtf(bx*bx + by*by + bz*bz);
        float tgt = bond_of(types[r], types[c]);
        float diff = cur - tgt;
        d2acc = diff * diff;
        float ratio = tgt / (cur + 1e-8f);
        ratio = fminf(fmaxf(ratio, 0.98f), 1.02f);
        float s = (ratio - 1.f) * 0.01f * 0.5f;
        atomicAdd(&pos2f[4*r],   bx * s);
        atomicAdd(&pos2f[4*r+1], by * s);
        atomicAdd(&pos2f[4*r+2], bz * s);
        atomicAdd(&pos2f[4*c],   -bx * s);
        atomicAdd(&pos2f[4*c+1], -by * s);
        atomicAdd(&pos2f[4*c+2], -bz * s);
    }
    float part = wave_reduce_sum(d2acc);
    if ((threadIdx.x & 63) == 0) atomicAdd(&lossAcc[1], part);
}

// ---- 6. steric clash: all-pairs, early-out before rsqrt, high occupancy ----
__global__ void __launch_bounds__(256, 8) k_steric(const float4* __restrict__ pos2,
                                                   float* __restrict__ csum,
                                                   float* __restrict__ svec,
                                                   float* __restrict__ lossAcc) {
    __shared__ float4 sm[JCHUNK];
    int i = blockIdx.x * 256 + threadIdx.x;
    float4 p = pos2[i];
    float ri08 = p.w;
    float cs = 0.f, sx = 0.f, sy = 0.f, sz = 0.f, ll = 0.f;
    int j0 = blockIdx.y * JCHUNK;
    if (threadIdx.x < JCHUNK) sm[threadIdx.x] = pos2[j0 + threadIdx.x];
    __syncthreads();
    #pragma unroll 4
    for (int jj = 0; jj < JCHUNK; jj++) {
        float4 q = sm[jj];
        float dx = p.x - q.x, dy = p.y - q.y, dz = p.z - q.z;
        float d2 = fmaf(dx, dx, fmaf(dy, dy, dz * dz));
        float md = ri08 + q.w;
        // hit iff dist < md  <=>  d2 < md^2 ; d2 > 1e-12 excludes exactly the
        // diagonal (bit-identical p/q -> d2 == 0; min real pair dist ~0.04)
        if (fmaf(md, md, -d2) > 0.f && d2 > 1e-12f) {
            float rinv = rsqrtf(d2);           // 1/dist
            float dist = d2 * rinv;            // sqrt(d2)
            float t1 = md - dist;
            ll = fmaf(t1, t1, ll);
            float coeff = t1 * 0.0025f * rinv;
            cs += coeff;
            sx = fmaf(coeff, q.x, sx);
            sy = fmaf(coeff, q.y, sy);
            sz = fmaf(coeff, q.z, sz);
        }
    }
    if (cs != 0.f) {
        atomicAdd(&csum[i], cs);
        atomicAdd(&svec[3*i],   sx);
        atomicAdd(&svec[3*i+1], sy);
        atomicAdd(&svec[3*i+2], sz);
    }
    float part = wave_reduce_sum(ll);
    if ((threadIdx.x & 63) == 0 && part != 0.f) atomicAdd(&lossAcc[2], part);
}

// ---- 7. final: out = pos2*(1+csum) - svec ; loss scalar ----
__global__ void k_final(const float4* __restrict__ pos2, const float* __restrict__ csum,
                        const float* __restrict__ svec, const float* __restrict__ lossAcc,
                        float* __restrict__ out) {
    int i = blockIdx.x * 256 + threadIdx.x;
    if (i < NA) {
        float4 p = pos2[i];
        float c = 1.f + csum[i];
        out[3*i]   = p.x * c - svec[3*i];
        out[3*i+1] = p.y * c - svec[3*i+1];
        out[3*i+2] = p.z * c - svec[3*i+2];
    }
    if (i == 0) {
        float loss = lossAcc[0] + lossAcc[1] * (1.f / NE) + lossAcc[2] * 0.5f;
        out[3*NA] = loss * 0.1f;
    }
}

extern "C" void kernel_launch(void* const* d_in, const int* in_sizes, int n_in,
                              void* d_out, int out_size, void* d_ws, size_t ws_size,
                              hipStream_t stream) {
    (void)in_sizes; (void)n_in; (void)out_size; (void)ws_size;
    const float* pos   = (const float*)d_in[0];
    const int*   eidx  = (const int*)d_in[1];
    const int*   types = (const int*)d_in[2];
    const int* row = eidx;
    const int* col = eidx + NE;

    int*   ws_i = (int*)d_ws;
    float* ws_f = (float*)d_ws;
    int*    deg     = ws_i + WS_DEG;
    float*  csum    = ws_f + WS_CSUM;
    float*  svec    = ws_f + WS_SVEC;
    float*  lossAcc = ws_f + WS_LOSS;
    float4* pos2    = (float4*)(ws_f + WS_POS2);
    float*  pos2f   = ws_f + WS_POS2;
    float*  pos1a   = ws_f + WS_POS1A;
    float*  pos1    = ws_f + WS_POS1;
    float*  viol    = ws_f + WS_VIOL;
    float*  rad08   = ws_f + WS_RAD;
    float*  out     = (float*)d_out;

    hipMemsetAsync(d_ws, 0, (size_t)WS_ZERO_END * 4, stream);
    k_degree<<<NE/256, 256, 0, stream>>>(row, deg);
    k_prep  <<<NA/256, 256, 0, stream>>>(deg, types, pos, viol, rad08,
                                         pos1a, pos1, pos2, lossAcc);
    k_pushA <<<NE/256, 256, 0, stream>>>(row, col, pos, viol, pos1a);
    k_pushB <<<NE/256, 256, 0, stream>>>(row, col, pos, viol, pos1a, pos1, pos2f);
    k_bond  <<<NE/256, 256, 0, stream>>>(row, col, types, pos1, pos2f, lossAcc);
    dim3 sg(NA/256, JSPLIT);
    k_steric<<<sg,     256, 0, stream>>>(pos2, csum, svec, lossAcc);
    k_final <<<NA/256, 256, 0, stream>>>(pos2, csum, svec, lossAcc, out);
}